// Round 6
// baseline (158.841 us; speedup 1.0000x reference)
//
#include <hip/hip_runtime.h>

#define N_COARSE 200000
#define D 128
#define RPT 8                                        // rows per thread
#define NCHUNK 8
#define CHUNK_ROWS ((N_COARSE + NCHUNK - 1) / NCHUNK)   // 25000 rows = 12.8 MB

typedef float v4f __attribute__((ext_vector_type(4)));
typedef int   v4i __attribute__((ext_vector_type(4)));

// Temporal chunking: launch p handles only rows whose index lies in x-chunk p
// (12.8 MB), so gather re-reads stay L3-resident and each x byte crosses HBM
// once per call instead of ~4x. Writes remain linear 512B rows (predicate is
// half-wave-uniform: all 32 lanes of a row agree). Shadow rows (idx==N_COARSE)
// are emitted by the first launch.
__global__ void nearest_upsample_chunk(const float* __restrict__ x,
                                       const int* __restrict__ idx,
                                       float* __restrict__ out,
                                       int M, int lo, int hi, int first) {
    int gid = blockIdx.x * blockDim.x + threadIdx.x;
    int Mg = (M + RPT - 1) / RPT;       // row groups
    int total = Mg * 32;
    if (gid >= total) return;

    int g = gid >> 5;                   // row group (8 consecutive rows)
    int c = gid & 31;                   // 16B slot within row

    const v4f* x4 = reinterpret_cast<const v4f*>(x);
    v4f* o4 = reinterpret_cast<v4f*>(out);
    const v4f zero = (v4f)(0.f);

    int r0 = g * RPT;
    // idx re-read every launch; plain loads so it stays cache-resident (3.2 MB)
    const v4i* idx4 = reinterpret_cast<const v4i*>(idx);
    v4i jA = idx4[(size_t)g * 2];
    v4i jB = idx4[(size_t)g * 2 + 1];
    int u[RPT] = {jA.x, jA.y, jA.z, jA.w, jB.x, jB.y, jB.z, jB.w};

    size_t ob = (size_t)r0 * 32 + c;
#pragma unroll
    for (int k = 0; k < RPT; ++k) {
        if (r0 + k >= M) break;
        int uk = u[k];
        if (uk >= lo && uk < hi) {
            v4f v = x4[(size_t)uk * 32 + c];
            __builtin_nontemporal_store(v, o4 + ob + (size_t)k * 32);
        } else if (first && (unsigned)uk >= (unsigned)N_COARSE) {
            __builtin_nontemporal_store(zero, o4 + ob + (size_t)k * 32);
        }
    }
}

extern "C" void kernel_launch(void* const* d_in, const int* in_sizes, int n_in,
                              void* d_out, int out_size, void* d_ws, size_t ws_size,
                              hipStream_t stream) {
    const float* x = (const float*)d_in[0];
    const int* idx = (const int*)d_in[1];
    float* out = (float*)d_out;

    int M = in_sizes[1];                // upsamples is [M, 1] -> M elements
    int Mg = (M + RPT - 1) / RPT;
    int total = Mg * 32;
    int block = 256;
    int grid = (total + block - 1) / block;

    for (int chunk = 0; chunk < NCHUNK; ++chunk) {
        int lo = chunk * CHUNK_ROWS;
        int hi = lo + CHUNK_ROWS;
        if (hi > N_COARSE) hi = N_COARSE;
        nearest_upsample_chunk<<<grid, block, 0, stream>>>(
            x, idx, out, M, lo, hi, chunk == 0 ? 1 : 0);
    }
}

// Round 8
// 118.704 us; speedup vs baseline: 1.3381x; 1.3381x over previous
//
#include <hip/hip_runtime.h>

#define N_COARSE 200000
#define D 128
#define RPT 16   // rows per thread

typedef float v4f __attribute__((ext_vector_type(4)));
typedef int   v4i __attribute__((ext_vector_type(4)));

// 32 lanes per row, one 16B chunk/lane/row. Each thread covers RPT consecutive
// rows at the same slot: 4x int4 idx loads + 16 independent gathers in flight
// (MLP=16). Shadow row (j==N_COARSE) handled by clamp+select so the gather
// loads stay unconditional. NT hint on stores (evict-first in L2; safe —
// still allocates/coherent, unlike sc0sc1 bypass which races the harness's
// dirty poison lines in L2).
__global__ void nearest_upsample_gather16(const float* __restrict__ x,
                                          const int* __restrict__ idx,
                                          float* __restrict__ out,
                                          int M) {
    int gid = blockIdx.x * blockDim.x + threadIdx.x;
    int Mg = (M + RPT - 1) / RPT;       // row groups
    int total = Mg * 32;
    if (gid >= total) return;

    int g = gid >> 5;                   // row group
    int c = gid & 31;                   // 16B slot within row

    const v4f* x4 = reinterpret_cast<const v4f*>(x);
    v4f* o4 = reinterpret_cast<v4f*>(out);
    const v4f zero = (v4f)(0.f);

    int r0 = g * RPT;

    if (r0 + RPT <= M) {
        // four int4 loads cover the 16 row indices (broadcast in-wave)
        const v4i* idx4 = reinterpret_cast<const v4i*>(idx);
        v4i j0 = __builtin_nontemporal_load(idx4 + (size_t)g * 4);
        v4i j1 = __builtin_nontemporal_load(idx4 + (size_t)g * 4 + 1);
        v4i j2 = __builtin_nontemporal_load(idx4 + (size_t)g * 4 + 2);
        v4i j3 = __builtin_nontemporal_load(idx4 + (size_t)g * 4 + 3);

        unsigned u[RPT] = {(unsigned)j0.x, (unsigned)j0.y, (unsigned)j0.z, (unsigned)j0.w,
                           (unsigned)j1.x, (unsigned)j1.y, (unsigned)j1.z, (unsigned)j1.w,
                           (unsigned)j2.x, (unsigned)j2.y, (unsigned)j2.z, (unsigned)j2.w,
                           (unsigned)j3.x, (unsigned)j3.y, (unsigned)j3.z, (unsigned)j3.w};

        v4f v[RPT];
#pragma unroll
        for (int k = 0; k < RPT; ++k) {
            unsigned kk = u[k] < N_COARSE ? u[k] : (N_COARSE - 1);
            v[k] = x4[(size_t)kk * 32 + c];     // 16 independent gathers in flight
        }
#pragma unroll
        for (int k = 0; k < RPT; ++k) {
            if (u[k] >= N_COARSE) v[k] = zero;  // shadow zero row
        }

        size_t ob = (size_t)r0 * 32 + c;
#pragma unroll
        for (int k = 0; k < RPT; ++k) {
            __builtin_nontemporal_store(v[k], o4 + ob + (size_t)k * 32);
        }
    } else {
        // tail: per-row scalar path
        for (int k = 0; k < RPT; ++k) {
            int r = r0 + k;
            if (r >= M) break;
            unsigned uu = (unsigned)idx[r];
            unsigned kk = uu < N_COARSE ? uu : (N_COARSE - 1);
            v4f v = x4[(size_t)kk * 32 + c];
            if (uu >= N_COARSE) v = zero;
            __builtin_nontemporal_store(v, o4 + (size_t)r * 32 + c);
        }
    }
}

extern "C" void kernel_launch(void* const* d_in, const int* in_sizes, int n_in,
                              void* d_out, int out_size, void* d_ws, size_t ws_size,
                              hipStream_t stream) {
    const float* x = (const float*)d_in[0];
    const int* idx = (const int*)d_in[1];
    float* out = (float*)d_out;

    int M = in_sizes[1];                // upsamples is [M, 1] -> M elements
    int Mg = (M + RPT - 1) / RPT;
    int total = Mg * 32;
    int block = 256;
    int grid = (total + block - 1) / block;

    nearest_upsample_gather16<<<grid, block, 0, stream>>>(x, idx, out, M);
}